// Round 10
// baseline (586.408 us; speedup 1.0000x reference)
//
#include <hip/hip_runtime.h>

#define NL 16384          // row length
#define NB 64             // rows = blocks
#define NT 1024           // threads per block (16 waves)
#define NC (NL / NT)      // 16 elements per thread
#define NW (NT / 64)      // 16 waves
#define N_ITER 12
#define N_IMFS 6

#pragma clang fp contract(off)   // everything unfused EXCEPT the explicit fmaf

// pad 4 floats per 32: keeps float4 (16B) alignment AND 2-way-max banking
#define HSZ (NL + ((NL >> 5) << 2))   // 18432
__device__ __forceinline__ int physi(int i) { return i + (((i) >> 5) << 2); }

// Frozen bit-exact semantics (certified R9, absmax 0.0):
//  strict peaks on f32 h; frac = (float)(i-l)/(float)max(den,1);
//  env = fmaf(frac, r-l, l); override ladder l<0 -> vr, n>=NL -> vl, tot<2 -> cummax/min;
//  mean = 0.5f*(envU+envL); h -= mean; freeze-h on converged iteration.
__global__ __launch_bounds__(NT, 4) void emd_main(
    const float* __restrict__ x, float* __restrict__ out,
    unsigned* cnt, double* sdsl, double* flsl) {
  __shared__ float h[HSZ];          // 73728 B
  __shared__ unsigned sc[HSZ];      // 73728 B: cold-path scratch (packed next / mean bits)
  __shared__ int wLU[NW], wLL[NW], wNU[NW], wNL[NW];
  __shared__ int eLU[NW], eLL[NW], eNU[NW], eNL[NW];
  __shared__ unsigned wCT[NW];
  __shared__ unsigned sTotS;
  __shared__ double tA[NW], tB[NW];
  __shared__ int sFlag;

  const int t = threadIdx.x;
  const int lane = t & 63;
  const int wv = t >> 6;
  const int row = blockIdx.x;
  const int base = t * NC;
  const float* xr = x + (size_t)row * NL;
  float* res = out + (size_t)N_IMFS * NB * NL + (size_t)row * NL;

  // init: strided global->LDS (coalesced); res slab = x
  for (int m = 0; m < NL / NT; m++) {
    int i = m * NT + t;
    float v = xr[i];
    h[physi(i)] = v;
    res[i] = v;
  }
  __syncthreads();
  // chunked register cache of own 16 elements (kept == LDS h at all times)
  float hreg[NC];
  #pragma unroll
  for (int q = 0; q < NC / 4; q++) {
    float4 v4 = *(const float4*)&h[physi(base + q * 4)];
    hreg[q*4+0]=v4.x; hreg[q*4+1]=v4.y; hreg[q*4+2]=v4.z; hreg[q*4+3]=v4.w;
  }

  unsigned ep = 0;
  bool done = false;

  for (int k = 0; k < N_IMFS; k++) {
    float* outk = out + (size_t)k * NB * NL + (size_t)row * NL;
    if (done) {  // globally-uniform skip (no barriers)
      for (int m = 0; m < NL / NT; m++) outk[m * NT + t] = 0.0f;
      continue;
    }

    // ---------------- sifting ----------------
    for (int it = 0; it < N_ITER; it++) {
      // halos (fresh each iteration; ordered by trailing syncthreads)
      float haloL = (base > 0) ? h[physi(base - 1)] : 0.0f;
      float haloR = (base + NC < NL) ? h[physi(base + NC)] : 0.0f;
      // peak masks from registers (identical f32 compares to R9)
      unsigned mU = 0, mL = 0;
      #pragma unroll
      for (int j = 0; j < NC; j++) {
        int i = base + j;
        if (i > 0 && i + 1 < NL) {
          float hm = (j > 0) ? hreg[j - 1] : haloL;
          float hc = hreg[j];
          float hp = (j < NC - 1) ? hreg[j + 1] : haloR;
          if (hm < hc && hc > hp) mU |= (1u << j);
          if (hm > hc && hc < hp) mL |= (1u << j);
        }
      }
      // chunk summaries (inclusive, matching certified R1/R5 scan semantics)
      int lmU = -1, lmL = -1, nUc = NL, nLc = NL;
      unsigned nreg[NC];
      #pragma unroll
      for (int j = NC - 1; j >= 0; j--) {
        if ((mU >> j) & 1) nUc = base + j;
        if ((mL >> j) & 1) nLc = base + j;
        nreg[j] = ((unsigned)nUc << 16) | (unsigned)nLc;
      }
      #pragma unroll
      for (int j = 0; j < NC; j++) {
        if ((mU >> j) & 1) lmU = base + j;
        if ((mL >> j) & 1) lmL = base + j;
      }
      unsigned ct = ((unsigned)__popc(mU) << 16) | (unsigned)__popc(mL);
      // wave-level scans (shuffles; no LDS, no barriers)
      int iLU = lmU, iLL = lmL, iNU = nUc, iNL = nLc;
      #pragma unroll
      for (int o = 1; o < 64; o <<= 1) {
        int a = __shfl_up(iLU, o, 64);
        int b = __shfl_up(iLL, o, 64);
        int c = __shfl_down(iNU, o, 64);
        int d = __shfl_down(iNL, o, 64);
        unsigned cc = __shfl_down(ct, o, 64);
        if (lane >= o) { iLU = max(iLU, a); iLL = max(iLL, b); }
        if (lane + o < 64) { iNU = min(iNU, c); iNL = min(iNL, d); ct += cc; }
      }
      if (lane == 63) { wLU[wv] = iLU; wLL[wv] = iLL; }
      if (lane == 0)  { wNU[wv] = iNU; wNL[wv] = iNL; wCT[wv] = ct; }
      __syncthreads();
      if (t == 0) {  // 16-entry serial combine
        int aLU = -1, aLL = -1; unsigned tot = 0;
        for (int w = 0; w < NW; w++) {
          eLU[w] = aLU; aLU = max(aLU, wLU[w]);
          eLL[w] = aLL; aLL = max(aLL, wLL[w]);
          tot += wCT[w];
        }
        int aNU = NL, aNL = NL;
        for (int w = NW - 1; w >= 0; w--) {
          eNU[w] = aNU; aNU = min(aNU, wNU[w]);
          eNL[w] = aNL; aNL = min(aNL, wNL[w]);
        }
        sTotS = tot;
      }
      __syncthreads();
      unsigned tot = sTotS;
      int totU = (int)(tot >> 16), totL = (int)(tot & 0xffffu);
      int pLU = __shfl_up(iLU, 1, 64); if (lane == 0) pLU = -1;
      int pLL = __shfl_up(iLL, 1, 64); if (lane == 0) pLL = -1;
      int sNUl = __shfl_down(iNU, 1, 64); if (lane == 63) sNUl = NL;
      int sNLl = __shfl_down(iNL, 1, 64); if (lane == 63) sNLl = NL;
      int clU = max(eLU[wv], pLU), clL = max(eLL[wv], pLL);
      int cnU = min(eNU[wv], sNUl), cnL = min(eNL[wv], sNLl);
      bool cold = (totU < 2) || (totL < 2);

      // pass C: envelopes + mean (frozen f32 semantics), endpoint gather caching
      float meanreg[NC];
      double pm2 = 0.0, ph2 = 0.0;
      if (!cold) {
        int lU = clU, lL = clL;
        int gLU = -0x7fffffff, gNU = -0x7fffffff, gLL = -0x7fffffff, gNL = -0x7fffffff;
        float vl = 0.0f, vr = 0.0f, wl = 0.0f, wr = 0.0f;
        #pragma unroll
        for (int j = 0; j < NC; j++) {
          int i = base + j;
          if ((mU >> j) & 1) lU = i;
          if ((mL >> j) & 1) lL = i;
          int nUv = (int)(nreg[j] >> 16);     if (cnU < nUv) nUv = cnU;
          int nLv = (int)(nreg[j] & 0xffffu); if (cnL < nLv) nLv = cnL;
          if (lU != gLU)  { gLU = lU;  vl = h[physi(lU < 0 ? 0 : lU)]; }
          if (nUv != gNU) { gNU = nUv; vr = h[physi(nUv >= NL ? NL - 1 : nUv)]; }
          if (lL != gLL)  { gLL = lL;  wl = h[physi(lL < 0 ? 0 : lL)]; }
          if (nLv != gNL) { gNL = nLv; wr = h[physi(nLv >= NL ? NL - 1 : nLv)]; }
          int den = nUv - lU;
          float fracU = (float)(i - lU) / (float)(den > 0 ? den : 1);
          float envU = (den > 0) ? __builtin_fmaf(fracU, vr - vl, vl) : vl;
          if (lU < 0) envU = vr;
          if (nUv >= NL) envU = vl;
          int den2 = nLv - lL;
          float fracL = (float)(i - lL) / (float)(den2 > 0 ? den2 : 1);
          float envL = (den2 > 0) ? __builtin_fmaf(fracL, wr - wl, wl) : wl;
          if (lL < 0) envL = wr;
          if (nLv >= NL) envL = wl;
          float mn = 0.5f * (envU + envL);
          meanreg[j] = mn;
          pm2 += (double)mn * (double)mn;
          ph2 += (double)hreg[j] * (double)hreg[j];
        }
      } else if (t == 0) {
        // cold fallback (<2 peaks): sequential, exact R9 ladder incl. cummax/cummin
        int nU2 = NL, nL2 = NL;
        for (int i = NL - 1; i >= 0; i--) {
          float hc = h[physi(i)];
          if (i > 0 && i + 1 < NL) {
            float hm = h[physi(i - 1)], hp = h[physi(i + 1)];
            if (hm < hc && hc > hp) nU2 = i;
            if (hm > hc && hc < hp) nL2 = i;
          }
          sc[physi(i)] = ((unsigned)nU2 << 16) | (unsigned)nL2;
        }
        int lU = -1, lL = -1;
        float rx = -3.402823466e38f, rn = 3.402823466e38f;
        for (int i = 0; i < NL; i++) {
          float hc = h[physi(i)];
          if (i > 0 && i + 1 < NL) {
            float hm = h[physi(i - 1)], hp = h[physi(i + 1)];
            if (hm < hc && hc > hp) lU = i;
            if (hm > hc && hc < hp) lL = i;
          }
          rx = fmaxf(rx, hc);
          rn = fminf(rn, hc);
          unsigned p = sc[physi(i)];
          int nUv = (int)(p >> 16), nLv = (int)(p & 0xffffu);
          float vl = h[physi(lU < 0 ? 0 : lU)];
          float vr = h[physi(nUv >= NL ? NL - 1 : nUv)];
          int den = nUv - lU;
          float fracU = (float)(i - lU) / (float)(den > 0 ? den : 1);
          float envU = (den > 0) ? __builtin_fmaf(fracU, vr - vl, vl) : vl;
          if (lU < 0) envU = vr;
          if (nUv >= NL) envU = vl;
          if (totU < 2) envU = rx;
          float wl = h[physi(lL < 0 ? 0 : lL)];
          float wr = h[physi(nLv >= NL ? NL - 1 : nLv)];
          int den2 = nLv - lL;
          float fracL = (float)(i - lL) / (float)(den2 > 0 ? den2 : 1);
          float envL = (den2 > 0) ? __builtin_fmaf(fracL, wr - wl, wl) : wl;
          if (lL < 0) envL = wr;
          if (nLv >= NL) envL = wl;
          if (totL < 2) envL = rn;
          float mn = 0.5f * (envU + envL);
          sc[physi(i)] = __float_as_uint(mn);
          pm2 += (double)mn * (double)mn;
          ph2 += (double)hc * (double)hc;
        }
      }
      // block reduce (pm2, ph2) — 2 barriers
      double bA = pm2, bB = ph2;
      #pragma unroll
      for (int o = 1; o < 64; o <<= 1) {
        double a = __shfl_down(bA, o, 64);
        double b = __shfl_down(bB, o, 64);
        if (lane + o < 64) { bA += a; bB += b; }
      }
      __syncthreads();
      if (lane == 0) { tA[wv] = bA; tB[wv] = bB; }
      __syncthreads();
      if (t == 0) {
        double sA = 0.0, sB = 0.0;
        for (int w = 0; w < NW; w++) { sA += tA[w]; sB += tB[w]; }
        atomicAdd(&sdsl[(k * N_ITER + it) * 2 + 0], sA);
        atomicAdd(&sdsl[(k * N_ITER + it) * 2 + 1], sB);
      }
      // ---- grid barrier + convergence decision ----
      ep++;
      __syncthreads();
      if (t == 0) {
        __hip_atomic_fetch_add(cnt, 1u, __ATOMIC_ACQ_REL, __HIP_MEMORY_SCOPE_AGENT);
        unsigned tgt = ep * gridDim.x;
        while (__hip_atomic_load(cnt, __ATOMIC_ACQUIRE, __HIP_MEMORY_SCOPE_AGENT) < tgt)
          __builtin_amdgcn_s_sleep(1);
        double m2 = __hip_atomic_load(&sdsl[(k * N_ITER + it) * 2 + 0],
                                      __ATOMIC_RELAXED, __HIP_MEMORY_SCOPE_AGENT);
        double h2 = __hip_atomic_load(&sdsl[(k * N_ITER + it) * 2 + 1],
                                      __ATOMIC_RELAXED, __HIP_MEMORY_SCOPE_AGENT);
        sFlag = (m2 / (h2 + 1e-8) < 0.05) ? 1 : 0;
      }
      __syncthreads();
      if (sFlag) break;   // converged: h frozen (JAX done-latch semantics)
      // subtract (registers + LDS writeback, float4)
      #pragma unroll
      for (int j = 0; j < NC; j++) {
        float mv = cold ? __uint_as_float(sc[physi(base + j)]) : meanreg[j];
        hreg[j] -= mv;
      }
      #pragma unroll
      for (int q = 0; q < NC / 4; q++) {
        float4 v4 = make_float4(hreg[q*4], hreg[q*4+1], hreg[q*4+2], hreg[q*4+3]);
        *(float4*)&h[physi(base + q * 4)] = v4;
      }
      __syncthreads();
    }

    // ------------- flatness test + outputs (f32 values, f64 sums) -------------
    float resv[NC];
    #pragma unroll
    for (int q = 0; q < NC / 4; q++) {
      float4 v4 = *(const float4*)&res[base + q * 4];
      resv[q*4+0]=v4.x; resv[q*4+1]=v4.y; resv[q*4+2]=v4.z; resv[q*4+3]=v4.w;
    }
    double s1 = 0.0, s2 = 0.0, s3 = 0.0, s4 = 0.0;
    #pragma unroll
    for (int j = 0; j < NC; j++) {
      int i = base + j;
      float rc = resv[j] - hreg[j];
      s1 += (double)rc;
      s2 += (double)rc * (double)rc;
      if (i + 1 < NL) {
        float rnx = (j + 1 < NC) ? (resv[j + 1] - hreg[j + 1])
                                 : (res[i + 1] - h[physi(i + 1)]);
        float d = rnx - rc;
        s3 += (double)d;
        s4 += (double)d * (double)d;
      }
    }
    // reduce (s1,s2) then (s3,s4)
    {
      double bA = s1, bB = s2;
      #pragma unroll
      for (int o = 1; o < 64; o <<= 1) {
        double a = __shfl_down(bA, o, 64);
        double b = __shfl_down(bB, o, 64);
        if (lane + o < 64) { bA += a; bB += b; }
      }
      __syncthreads();
      if (lane == 0) { tA[wv] = bA; tB[wv] = bB; }
      __syncthreads();
      if (t == 0) {
        double sA = 0.0, sB = 0.0;
        for (int w = 0; w < NW; w++) { sA += tA[w]; sB += tB[w]; }
        atomicAdd(&flsl[k * 4 + 0], sA);
        atomicAdd(&flsl[k * 4 + 1], sB);
      }
      bA = s3; bB = s4;
      #pragma unroll
      for (int o = 1; o < 64; o <<= 1) {
        double a = __shfl_down(bA, o, 64);
        double b = __shfl_down(bB, o, 64);
        if (lane + o < 64) { bA += a; bB += b; }
      }
      __syncthreads();
      if (lane == 0) { tA[wv] = bA; tB[wv] = bB; }
      __syncthreads();
      if (t == 0) {
        double sA = 0.0, sB = 0.0;
        for (int w = 0; w < NW; w++) { sA += tA[w]; sB += tB[w]; }
        atomicAdd(&flsl[k * 4 + 2], sA);
        atomicAdd(&flsl[k * 4 + 3], sB);
      }
    }
    // outputs: IMF k = h; res -= h; h <- res (the reduces above ordered the
    // cross-thread reads of res/h before these writes)
    #pragma unroll
    for (int q = 0; q < NC / 4; q++) {
      float4 hv = make_float4(hreg[q*4], hreg[q*4+1], hreg[q*4+2], hreg[q*4+3]);
      float4 rq;
      rq.x = resv[q*4+0] - hv.x; rq.y = resv[q*4+1] - hv.y;
      rq.z = resv[q*4+2] - hv.z; rq.w = resv[q*4+3] - hv.w;
      *(float4*)&outk[base + q * 4] = hv;
      *(float4*)&res[base + q * 4] = rq;
      *(float4*)&h[physi(base + q * 4)] = rq;
      hreg[q*4+0]=rq.x; hreg[q*4+1]=rq.y; hreg[q*4+2]=rq.z; hreg[q*4+3]=rq.w;
    }
    // ---- grid barrier + flatness decision ----
    ep++;
    __syncthreads();
    if (t == 0) {
      __hip_atomic_fetch_add(cnt, 1u, __ATOMIC_ACQ_REL, __HIP_MEMORY_SCOPE_AGENT);
      unsigned tgt = ep * gridDim.x;
      while (__hip_atomic_load(cnt, __ATOMIC_ACQUIRE, __HIP_MEMORY_SCOPE_AGENT) < tgt)
        __builtin_amdgcn_s_sleep(1);
      double S1 = __hip_atomic_load(&flsl[k * 4 + 0], __ATOMIC_RELAXED, __HIP_MEMORY_SCOPE_AGENT);
      double S2 = __hip_atomic_load(&flsl[k * 4 + 1], __ATOMIC_RELAXED, __HIP_MEMORY_SCOPE_AGENT);
      double S3 = __hip_atomic_load(&flsl[k * 4 + 2], __ATOMIC_RELAXED, __HIP_MEMORY_SCOPE_AGENT);
      double S4 = __hip_atomic_load(&flsl[k * 4 + 3], __ATOMIC_RELAXED, __HIP_MEMORY_SCOPE_AGENT);
      double nr = (double)NB * (double)NL;
      double nd = (double)NB * (double)(NL - 1);
      double varr = (S2 - S1 * S1 / nr) / (nr - 1.0);
      double vard = (S4 - S3 * S3 / nd) / (nd - 1.0);
      sFlag = (vard < 0.05 * varr) ? 1 : 0;
    }
    __syncthreads();
    done = done || (sFlag != 0);
  }
}

extern "C" void kernel_launch(void* const* d_in, const int* in_sizes, int n_in,
                              void* d_out, int out_size, void* d_ws, size_t ws_size,
                              hipStream_t stream) {
  const float* x = (const float*)d_in[0];
  float* out = (float*)d_out;
  // ws layout: [0] barrier counter; [256] sd slots (6*12*2 dbl); [1408] flat slots (6*4 dbl)
  size_t zb = ws_size < 4096 ? ws_size : 4096;
  hipMemsetAsync(d_ws, 0, zb, stream);
  unsigned* cnt = (unsigned*)d_ws;
  double* sdsl = (double*)((char*)d_ws + 256);
  double* flsl = (double*)((char*)d_ws + 256 + (size_t)N_IMFS * N_ITER * 2 * 8);
  hipLaunchKernelGGL(emd_main, dim3(NB), dim3(NT), 0, stream, x, out, cnt, sdsl, flsl);
}